// Round 1
// baseline (2943.304 us; speedup 1.0000x reference)
//
#include <hip/hip_runtime.h>
#include <hip/hip_bf16.h>

#define EMB_DIM 64

// ---------------- degree: one thread per edge, atomic count into deg[col] ----
__global__ void deg_kernel(const int* __restrict__ col, float* __restrict__ deg, int E) {
    int e = blockIdx.x * blockDim.x + threadIdx.x;
    if (e < E) {
        unsafeAtomicAdd(&deg[col[e]], 1.0f);
    }
}

// ---------------- dis[i] = deg>0 ? deg^-0.5 : 0 ------------------------------
__global__ void dis_kernel(const float* __restrict__ deg, float* __restrict__ dis, int N) {
    int i = blockIdx.x * blockDim.x + threadIdx.x;
    if (i < N) {
        float d = deg[i];
        dis[i] = (d > 0.0f) ? (1.0f / sqrtf(d)) : 0.0f;
    }
}

// ---------------- scatter: one wave per edge, lane = embedding dim ----------
// dst[col[e], lane] += dis[row]*dis[col] * src[row[e], lane]
__global__ void scatter_kernel(const int* __restrict__ row, const int* __restrict__ col,
                               const float* __restrict__ dis,
                               const float* __restrict__ src, float* __restrict__ dst,
                               int E) {
    int wave = (blockIdx.x * blockDim.x + threadIdx.x) >> 6;
    int lane = threadIdx.x & 63;
    if (wave >= E) return;
    int r = row[wave];
    int c = col[wave];
    float norm = dis[r] * dis[c];
    float v = norm * src[(size_t)r * EMB_DIM + lane];
    unsafeAtomicAdd(&dst[(size_t)c * EMB_DIM + lane], v);
}

// ---------------- out = a + b  (float4 vectorized) ---------------------------
__global__ void add2_kernel(const float4* __restrict__ a, const float4* __restrict__ b,
                            float4* __restrict__ out, int n4) {
    int i = blockIdx.x * blockDim.x + threadIdx.x;
    if (i < n4) {
        float4 x = a[i], y = b[i];
        out[i] = make_float4(x.x + y.x, x.y + y.y, x.z + y.z, x.w + y.w);
    }
}

// ---------------- out += b ---------------------------------------------------
__global__ void acc_kernel(float4* __restrict__ out, const float4* __restrict__ b, int n4) {
    int i = blockIdx.x * blockDim.x + threadIdx.x;
    if (i < n4) {
        float4 x = out[i], y = b[i];
        out[i] = make_float4(x.x + y.x, x.y + y.y, x.z + y.z, x.w + y.w);
    }
}

// ---------------- out = (out + b) * 0.25 -------------------------------------
__global__ void final_kernel(float4* __restrict__ out, const float4* __restrict__ b, int n4) {
    int i = blockIdx.x * blockDim.x + threadIdx.x;
    if (i < n4) {
        float4 x = out[i], y = b[i];
        out[i] = make_float4((x.x + y.x) * 0.25f, (x.y + y.y) * 0.25f,
                             (x.z + y.z) * 0.25f, (x.w + y.w) * 0.25f);
    }
}

extern "C" void kernel_launch(void* const* d_in, const int* in_sizes, int n_in,
                              void* d_out, int out_size, void* d_ws, size_t ws_size,
                              hipStream_t stream) {
    const int* edge = (const int*)d_in[0];
    const float* emb = (const float*)d_in[1];
    const int E = in_sizes[0] / 2;           // 4,000,000
    const int N = in_sizes[1] / EMB_DIM;     // 150,000
    float* out = (float*)d_out;

    // workspace layout: A[N*64] | B[N*64] | deg[N] | dis[N]
    float* A   = (float*)d_ws;
    float* B   = A + (size_t)N * EMB_DIM;
    float* deg = B + (size_t)N * EMB_DIM;
    float* dis = deg + N;

    const int* row = edge;
    const int* col = edge + E;

    const size_t emb_bytes = (size_t)N * EMB_DIM * sizeof(float);
    const int n4 = N * EMB_DIM / 4;

    const int TPB = 256;
    const int edge_blocks   = (E + TPB - 1) / TPB;          // 1 thread / edge
    const int wave_blocks   = (E + 3) / 4;                  // 1 wave / edge, 4 waves/block
    const int node_blocks   = (N + TPB - 1) / TPB;
    const int vec_blocks    = (n4 + TPB - 1) / TPB;

    // degree + normalization
    hipMemsetAsync(deg, 0, (size_t)N * sizeof(float), stream);
    deg_kernel<<<edge_blocks, TPB, 0, stream>>>(col, deg, E);
    dis_kernel<<<node_blocks, TPB, 0, stream>>>(deg, dis, N);

    // layer 1: A = P(emb);  out = emb + A
    hipMemsetAsync(A, 0, emb_bytes, stream);
    scatter_kernel<<<wave_blocks, TPB, 0, stream>>>(row, col, dis, emb, A, E);
    add2_kernel<<<vec_blocks, TPB, 0, stream>>>((const float4*)emb, (const float4*)A,
                                                (float4*)out, n4);

    // layer 2: B = P(A);  out += B
    hipMemsetAsync(B, 0, emb_bytes, stream);
    scatter_kernel<<<wave_blocks, TPB, 0, stream>>>(row, col, dis, A, B, E);
    acc_kernel<<<vec_blocks, TPB, 0, stream>>>((float4*)out, (const float4*)B, n4);

    // layer 3: A = P(B);  out = (out + A) / 4
    hipMemsetAsync(A, 0, emb_bytes, stream);
    scatter_kernel<<<wave_blocks, TPB, 0, stream>>>(row, col, dis, B, A, E);
    final_kernel<<<vec_blocks, TPB, 0, stream>>>((float4*)out, (const float4*)A, n4);
}

// Round 2
// 1165.472 us; speedup vs baseline: 2.5254x; 2.5254x over previous
//
#include <hip/hip_runtime.h>

#define D 64
constexpr int TPB = 256;

// ---------------- histogram of destination degrees ---------------------------
__global__ void hist_kernel(const int* __restrict__ col, int* __restrict__ deg, int E) {
    int e = blockIdx.x * blockDim.x + threadIdx.x;
    if (e < E) atomicAdd(&deg[col[e]], 1);
}

// ---------------- dis[i] = deg>0 ? deg^-0.5 : 0 ------------------------------
__global__ void dis_kernel(const int* __restrict__ deg, float* __restrict__ dis, int N) {
    int i = blockIdx.x * blockDim.x + threadIdx.x;
    if (i < N) {
        int d = deg[i];
        dis[i] = (d > 0) ? rsqrtf((float)d) : 0.0f;
    }
}

// ---------------- scan stage 1: per-block inclusive scan + block sums --------
__global__ void scan1_kernel(const int* __restrict__ deg, int* __restrict__ part,
                             int* __restrict__ bsum, int N) {
    __shared__ int s[TPB];
    int t = threadIdx.x;
    int i = blockIdx.x * TPB + t;
    int v = (i < N) ? deg[i] : 0;
    s[t] = v;
    __syncthreads();
    for (int off = 1; off < TPB; off <<= 1) {
        int x = (t >= off) ? s[t - off] : 0;
        __syncthreads();
        s[t] += x;
        __syncthreads();
    }
    if (i < N) part[i] = s[t];
    if (t == TPB - 1) bsum[blockIdx.x] = s[t];
}

// ---------------- scan stage 2: exclusive scan of block sums (single block) --
__global__ void scan2_kernel(const int* __restrict__ bsum, int* __restrict__ boff, int nb) {
    __shared__ int s[1024];
    int t = threadIdx.x;
    int v = (t < nb) ? bsum[t] : 0;
    s[t] = v;
    __syncthreads();
    for (int off = 1; off < 1024; off <<= 1) {
        int x = (t >= off) ? s[t - off] : 0;
        __syncthreads();
        s[t] += x;
        __syncthreads();
    }
    if (t < nb) boff[t] = s[t] - v;   // exclusive
}

// ---------------- scan stage 3: row_ptr = boff[b] + part[i] - deg[i] ---------
__global__ void scan3_kernel(const int* __restrict__ deg, const int* __restrict__ part,
                             const int* __restrict__ boff, int* __restrict__ row_ptr,
                             int N, int E) {
    int i = blockIdx.x * blockDim.x + threadIdx.x;
    if (i < N) row_ptr[i] = boff[blockIdx.x] + part[i] - deg[i];
    if (i == 0) row_ptr[N] = E;
}

// ---------------- placement: counting-sort rows by destination ---------------
__global__ void place_kernel(const int* __restrict__ row, const int* __restrict__ col,
                             const int* __restrict__ row_ptr, int* __restrict__ cursor,
                             int* __restrict__ srow, int E) {
    int e = blockIdx.x * blockDim.x + threadIdx.x;
    if (e < E) {
        int c = col[e];
        int p = row_ptr[c] + atomicAdd(&cursor[c], 1);
        srow[p] = row[e];
    }
}

// ---------------- Z0 = dis ⊙ emb (row-scaled embedding) ----------------------
__global__ void z0_kernel(const float4* __restrict__ emb, const float* __restrict__ dis,
                          float4* __restrict__ z, int n4) {
    int i = blockIdx.x * blockDim.x + threadIdx.x;
    if (i < n4) {
        float d = dis[i >> 4];            // 16 float4 per node
        float4 x = emb[i];
        z[i] = make_float4(d * x.x, d * x.y, d * x.z, d * x.w);
    }
}

// ---------------- CSR SpMM: one wave per destination node, lane = dim --------
// acc = sum over incoming edges of src[r] (src is pre-scaled by dis[r])
// embs = dis[c]*acc; dst = dis[c]*embs (pre-scaled for next layer)
// MODE 0: out = emb + embs | MODE 1: out += embs | MODE 2: out = (out+embs)*0.25
template <int MODE, bool WRITE_DST>
__global__ void spmm_kernel(const int* __restrict__ row_ptr, const int* __restrict__ srow,
                            const float* __restrict__ dis,
                            const float* __restrict__ src, float* __restrict__ dst,
                            float* __restrict__ out, const float* __restrict__ emb, int N) {
    int wave = (blockIdx.x * blockDim.x + threadIdx.x) >> 6;
    int lane = threadIdx.x & 63;
    if (wave >= N) return;
    int start = row_ptr[wave];
    int end   = row_ptr[wave + 1];
    float acc = 0.0f;
    for (int base = start; base < end; base += 64) {
        int mye = base + lane;
        int rr = (mye < end) ? srow[mye] : 0;   // coalesced edge-index load
        int cnt = min(64, end - base);
        for (int j = 0; j < cnt; ++j) {
            int r = __shfl(rr, j);              // broadcast via readlane
            acc += src[(size_t)r * D + lane];   // contiguous 256B gather per wave
        }
    }
    float dc = dis[wave];
    float embs = dc * acc;
    size_t o = (size_t)wave * D + lane;
    if (WRITE_DST) dst[o] = dc * embs;
    if (MODE == 0)      out[o] = emb[o] + embs;
    else if (MODE == 1) out[o] += embs;
    else                out[o] = (out[o] + embs) * 0.25f;
}

extern "C" void kernel_launch(void* const* d_in, const int* in_sizes, int n_in,
                              void* d_out, int out_size, void* d_ws, size_t ws_size,
                              hipStream_t stream) {
    const int* edge = (const int*)d_in[0];
    const float* emb = (const float*)d_in[1];
    const int E = in_sizes[0] / 2;       // 4,000,000
    const int N = in_sizes[1] / D;       // 150,000
    float* out = (float*)d_out;

    const int* row = edge;
    const int* col = edge + E;

    // workspace layout
    float* A       = (float*)d_ws;                 // N*64 floats (Z ping)
    float* B       = A + (size_t)N * D;            // N*64 floats (Z pong)
    int*   srow    = (int*)(B + (size_t)N * D);    // E ints (sorted rows)
    int*   row_ptr = srow + E;                     // N+1 ints
    int*   deg     = row_ptr + N + 1;              // N ints
    int*   part    = deg + N;                      // N ints (block-scan partials)
    int*   cursor  = part + N;                     // N ints
    float* dis     = (float*)(cursor + N);         // N floats
    int*   bsum    = (int*)(dis + N);              // nb ints
    const int nb = (N + TPB - 1) / TPB;            // 586
    int*   boff    = bsum + nb;                    // nb ints

    const int edge_blocks = (E + TPB - 1) / TPB;
    const int node_blocks = nb;
    const int n4 = N * D / 4;
    const int vec_blocks = (n4 + TPB - 1) / TPB;
    const int spmm_blocks = (N * 64 + TPB - 1) / TPB;   // 1 wave per node

    // ---- build normalization + CSR (per-call; structure inputs may be re-restored)
    hipMemsetAsync(deg, 0, (size_t)N * sizeof(int), stream);
    hist_kernel<<<edge_blocks, TPB, 0, stream>>>(col, deg, E);
    dis_kernel<<<node_blocks, TPB, 0, stream>>>(deg, dis, N);
    scan1_kernel<<<node_blocks, TPB, 0, stream>>>(deg, part, bsum, N);
    scan2_kernel<<<1, 1024, 0, stream>>>(bsum, boff, nb);
    scan3_kernel<<<node_blocks, TPB, 0, stream>>>(deg, part, boff, row_ptr, N, E);
    hipMemsetAsync(cursor, 0, (size_t)N * sizeof(int), stream);
    place_kernel<<<edge_blocks, TPB, 0, stream>>>(row, col, row_ptr, cursor, srow, E);

    // ---- Z0 = dis ⊙ emb
    z0_kernel<<<vec_blocks, TPB, 0, stream>>>((const float4*)emb, dis, (float4*)A, n4);

    // ---- layer 1: out = emb + dis[c]*ΣA ; B = pre-scaled next state
    spmm_kernel<0, true><<<spmm_blocks, TPB, 0, stream>>>(row_ptr, srow, dis, A, B, out, emb, N);
    // ---- layer 2: out += ; A = next state
    spmm_kernel<1, true><<<spmm_blocks, TPB, 0, stream>>>(row_ptr, srow, dis, B, A, out, emb, N);
    // ---- layer 3: out = (out + embs) * 0.25 ; no dst
    spmm_kernel<2, false><<<spmm_blocks, TPB, 0, stream>>>(row_ptr, srow, dis, A, nullptr, out, emb, N);
}

// Round 5
// 1136.787 us; speedup vs baseline: 2.5891x; 1.0252x over previous
//
#include <hip/hip_runtime.h>
#include <hip/hip_fp16.h>

#define D 64
constexpr int TPB = 256;
typedef unsigned short u16;

// ---------------- histogram of destination degrees ---------------------------
__global__ void hist_kernel(const int* __restrict__ col, int* __restrict__ deg, int E) {
    int e = blockIdx.x * blockDim.x + threadIdx.x;
    if (e < E) atomicAdd(&deg[col[e]], 1);
}

// ---------------- dis[i] = deg>0 ? deg^-0.5 : 0 ------------------------------
__global__ void dis_kernel(const int* __restrict__ deg, float* __restrict__ dis, int N) {
    int i = blockIdx.x * blockDim.x + threadIdx.x;
    if (i < N) {
        int d = deg[i];
        dis[i] = (d > 0) ? rsqrtf((float)d) : 0.0f;
    }
}

// ---------------- scan stage 1: per-block inclusive scan + block sums --------
__global__ void scan1_kernel(const int* __restrict__ deg, int* __restrict__ part,
                             int* __restrict__ bsum, int N) {
    __shared__ int s[TPB];
    int t = threadIdx.x;
    int i = blockIdx.x * TPB + t;
    int v = (i < N) ? deg[i] : 0;
    s[t] = v;
    __syncthreads();
    for (int off = 1; off < TPB; off <<= 1) {
        int x = (t >= off) ? s[t - off] : 0;
        __syncthreads();
        s[t] += x;
        __syncthreads();
    }
    if (i < N) part[i] = s[t];
    if (t == TPB - 1) bsum[blockIdx.x] = s[t];
}

// ---------------- scan stage 2: exclusive scan of block sums (single block) --
__global__ void scan2_kernel(const int* __restrict__ bsum, int* __restrict__ boff, int nb) {
    __shared__ int s[1024];
    int t = threadIdx.x;
    int v = (t < nb) ? bsum[t] : 0;
    s[t] = v;
    __syncthreads();
    for (int off = 1; off < 1024; off <<= 1) {
        int x = (t >= off) ? s[t - off] : 0;
        __syncthreads();
        s[t] += x;
        __syncthreads();
    }
    if (t < nb) boff[t] = s[t] - v;   // exclusive
}

// ---------------- scan stage 3: row_ptr = boff[b] + part[i] - deg[i] ---------
__global__ void scan3_kernel(const int* __restrict__ deg, const int* __restrict__ part,
                             const int* __restrict__ boff, int* __restrict__ row_ptr,
                             int N, int E) {
    int i = blockIdx.x * blockDim.x + threadIdx.x;
    if (i < N) row_ptr[i] = boff[blockIdx.x] + part[i] - deg[i];
    if (i == 0) row_ptr[N] = E;
}

// ---------------- placement: counting-sort rows by destination ---------------
__global__ void place_kernel(const int* __restrict__ row, const int* __restrict__ col,
                             const int* __restrict__ row_ptr, int* __restrict__ cursor,
                             int* __restrict__ srow, int E) {
    int e = blockIdx.x * blockDim.x + threadIdx.x;
    if (e < E) {
        int c = col[e];
        int p = row_ptr[c] + atomicAdd(&cursor[c], 1);
        srow[p] = row[e];
    }
}

// ---------------- Z0 = fp16(dis ⊙ emb): one thread per element ---------------
__global__ void z0_kernel(const float* __restrict__ emb, const float* __restrict__ dis,
                          u16* __restrict__ z, int n) {
    int i = blockIdx.x * blockDim.x + threadIdx.x;
    if (i < n) {
        float d = dis[i >> 6];            // 64 floats per node
        z[i] = __half_as_ushort(__float2half_rn(d * emb[i]));
    }
}

// ---------------- CSR SpMM: one wave per destination node, lane = dim --------
// Structure identical to the round-2 passing kernel; only the gathered element
// is fp16 (128 B/row = one cache line) instead of fp32. acc stays fp32.
// src is pre-scaled by dis[r]; embs = dis[c]*acc; dst = fp16(dis[c]*embs).
// MODE 0: out = emb + embs | MODE 1: out += embs | MODE 2: out = (out+embs)*0.25
template <int MODE, bool WRITE_DST>
__global__ void spmm_kernel(const int* __restrict__ row_ptr, const int* __restrict__ srow,
                            const float* __restrict__ dis,
                            const u16* __restrict__ src, u16* __restrict__ dst,
                            float* __restrict__ out, const float* __restrict__ emb, int N) {
    int wave = (blockIdx.x * blockDim.x + threadIdx.x) >> 6;
    int lane = threadIdx.x & 63;
    if (wave >= N) return;
    int start = row_ptr[wave];
    int end   = row_ptr[wave + 1];
    float acc = 0.0f;
    for (int base = start; base < end; base += 64) {
        int mye = base + lane;
        int rr = (mye < end) ? srow[mye] : 0;   // coalesced edge-index load
        int cnt = min(64, end - base);
        for (int j = 0; j < cnt; ++j) {
            int r = __shfl(rr, j);              // wave-uniform broadcast
            u16 u = src[(size_t)r * D + lane];  // fp16, 128B/row = 1 line
            acc += __half2float(__ushort_as_half(u));
        }
    }
    float dc = dis[wave];
    float embs = dc * acc;
    size_t o = (size_t)wave * D + lane;
    if (WRITE_DST) dst[o] = __half_as_ushort(__float2half_rn(dc * embs));
    if (MODE == 0)      out[o] = emb[o] + embs;
    else if (MODE == 1) out[o] += embs;
    else                out[o] = (out[o] + embs) * 0.25f;
}

extern "C" void kernel_launch(void* const* d_in, const int* in_sizes, int n_in,
                              void* d_out, int out_size, void* d_ws, size_t ws_size,
                              hipStream_t stream) {
    const int* edge = (const int*)d_in[0];
    const float* emb = (const float*)d_in[1];
    const int E = in_sizes[0] / 2;       // 4,000,000
    const int N = in_sizes[1] / D;       // 150,000
    float* out = (float*)d_out;

    const int* row = edge;
    const int* col = edge + E;

    // workspace layout
    u16*   A       = (u16*)d_ws;                   // N*64 fp16 (Z ping)
    u16*   B       = A + (size_t)N * D;            // N*64 fp16 (Z pong)
    int*   srow    = (int*)(B + (size_t)N * D);    // E ints (sorted rows)
    int*   row_ptr = srow + E;                     // N+1 ints
    int*   deg     = row_ptr + N + 1;              // N ints
    int*   part    = deg + N;                      // N ints
    int*   cursor  = part + N;                     // N ints
    float* dis     = (float*)(cursor + N);         // N floats
    int*   bsum    = (int*)(dis + N);              // nb ints
    const int nb = (N + TPB - 1) / TPB;            // 586
    int*   boff    = bsum + nb;                    // nb ints

    const int edge_blocks = (E + TPB - 1) / TPB;
    const int node_blocks = nb;
    const int n = N * D;
    const int z_blocks = (n + TPB - 1) / TPB;
    const int spmm_blocks = (N * 64 + TPB - 1) / TPB;   // 1 wave per node

    // ---- build normalization + CSR (round-2-exact)
    hipMemsetAsync(deg, 0, (size_t)N * sizeof(int), stream);
    hist_kernel<<<edge_blocks, TPB, 0, stream>>>(col, deg, E);
    dis_kernel<<<node_blocks, TPB, 0, stream>>>(deg, dis, N);
    scan1_kernel<<<node_blocks, TPB, 0, stream>>>(deg, part, bsum, N);
    scan2_kernel<<<1, 1024, 0, stream>>>(bsum, boff, nb);
    scan3_kernel<<<node_blocks, TPB, 0, stream>>>(deg, part, boff, row_ptr, N, E);
    hipMemsetAsync(cursor, 0, (size_t)N * sizeof(int), stream);
    place_kernel<<<edge_blocks, TPB, 0, stream>>>(row, col, row_ptr, cursor, srow, E);

    // ---- Z0 = fp16(dis ⊙ emb)
    z0_kernel<<<z_blocks, TPB, 0, stream>>>(emb, dis, A, n);

    // ---- layer 1: out = emb + embs ; B = pre-scaled next state (fp16)
    spmm_kernel<0, true><<<spmm_blocks, TPB, 0, stream>>>(row_ptr, srow, dis, A, B,
                                                          out, emb, N);
    // ---- layer 2: out += embs ; A = next state
    spmm_kernel<1, true><<<spmm_blocks, TPB, 0, stream>>>(row_ptr, srow, dis, B, A,
                                                          out, emb, N);
    // ---- layer 3: out = (out + embs) * 0.25
    spmm_kernel<2, false><<<spmm_blocks, TPB, 0, stream>>>(row_ptr, srow, dis, A, nullptr,
                                                           out, emb, N);
}

// Round 6
// 783.893 us; speedup vs baseline: 3.7547x; 1.4502x over previous
//
#include <hip/hip_runtime.h>
#include <hip/hip_fp16.h>

#define D 64
constexpr int TPB = 256;
typedef unsigned short u16;

// ---------------- histogram of destination degrees ---------------------------
__global__ void hist_kernel(const int* __restrict__ col, int* __restrict__ deg, int E) {
    int e = blockIdx.x * blockDim.x + threadIdx.x;
    if (e < E) atomicAdd(&deg[col[e]], 1);
}

// ---------------- dis[i] = deg>0 ? deg^-0.5 : 0 ------------------------------
__global__ void dis_kernel(const int* __restrict__ deg, float* __restrict__ dis, int N) {
    int i = blockIdx.x * blockDim.x + threadIdx.x;
    if (i < N) {
        int d = deg[i];
        dis[i] = (d > 0) ? rsqrtf((float)d) : 0.0f;
    }
}

// ---------------- scan stage 1: per-block inclusive scan + block sums --------
__global__ void scan1_kernel(const int* __restrict__ deg, int* __restrict__ part,
                             int* __restrict__ bsum, int N) {
    __shared__ int s[TPB];
    int t = threadIdx.x;
    int i = blockIdx.x * TPB + t;
    int v = (i < N) ? deg[i] : 0;
    s[t] = v;
    __syncthreads();
    for (int off = 1; off < TPB; off <<= 1) {
        int x = (t >= off) ? s[t - off] : 0;
        __syncthreads();
        s[t] += x;
        __syncthreads();
    }
    if (i < N) part[i] = s[t];
    if (t == TPB - 1) bsum[blockIdx.x] = s[t];
}

// ---------------- scan stage 2: exclusive scan of block sums (single block) --
__global__ void scan2_kernel(const int* __restrict__ bsum, int* __restrict__ boff, int nb) {
    __shared__ int s[1024];
    int t = threadIdx.x;
    int v = (t < nb) ? bsum[t] : 0;
    s[t] = v;
    __syncthreads();
    for (int off = 1; off < 1024; off <<= 1) {
        int x = (t >= off) ? s[t - off] : 0;
        __syncthreads();
        s[t] += x;
        __syncthreads();
    }
    if (t < nb) boff[t] = s[t] - v;   // exclusive
}

// ---------------- scan stage 3: row_ptr = boff[b] + part[i] - deg[i] ---------
__global__ void scan3_kernel(const int* __restrict__ deg, const int* __restrict__ part,
                             const int* __restrict__ boff, int* __restrict__ row_ptr,
                             int N, int E) {
    int i = blockIdx.x * blockDim.x + threadIdx.x;
    if (i < N) row_ptr[i] = boff[blockIdx.x] + part[i] - deg[i];
    if (i == 0) row_ptr[N] = E;
}

// ---------------- placement: counting-sort rows by destination ---------------
__global__ void place_kernel(const int* __restrict__ row, const int* __restrict__ col,
                             const int* __restrict__ row_ptr, int* __restrict__ cursor,
                             int* __restrict__ srow, int E) {
    int e = blockIdx.x * blockDim.x + threadIdx.x;
    if (e < E) {
        int c = col[e];
        int p = row_ptr[c] + atomicAdd(&cursor[c], 1);
        srow[p] = row[e];
    }
}

// ---------------- Z0 = fp16(dis ⊙ emb): one thread per element ---------------
__global__ void z0_kernel(const float* __restrict__ emb, const float* __restrict__ dis,
                          u16* __restrict__ z, int n) {
    int i = blockIdx.x * blockDim.x + threadIdx.x;
    if (i < n) {
        float d = dis[i >> 6];            // 64 floats per node
        z[i] = __half_as_ushort(__float2half_rn(d * emb[i]));
    }
}

// ---------------- CSR SpMM: one wave per destination node, lane = dim --------
// Gather loop unrolled by 8 with independent destination registers so each
// wave keeps ~8 VMEM loads in flight (round-5 version had ~1 → latency-bound).
// src is pre-scaled by dis[r]; embs = dis[c]*acc; dst = fp16(dis[c]*embs).
// MODE 0: out = emb + embs | MODE 1: out += embs | MODE 2: out = (out+embs)*0.25
template <int MODE, bool WRITE_DST>
__global__ void spmm_kernel(const int* __restrict__ row_ptr, const int* __restrict__ srow,
                            const float* __restrict__ dis,
                            const u16* __restrict__ src, u16* __restrict__ dst,
                            float* __restrict__ out, const float* __restrict__ emb, int N) {
    int wave = (blockIdx.x * blockDim.x + threadIdx.x) >> 6;
    int lane = threadIdx.x & 63;
    if (wave >= N) return;
    int start = row_ptr[wave];
    int end   = row_ptr[wave + 1];
    float acc = 0.0f;
    for (int base = start; base < end; base += 64) {
        int mye = base + lane;
        int rr = (mye < end) ? srow[mye] : 0;   // coalesced edge-index load
        int cnt = min(64, end - base);
        int j = 0;
        for (; j + 8 <= cnt; j += 8) {
            int r0 = __shfl(rr, j + 0);
            int r1 = __shfl(rr, j + 1);
            int r2 = __shfl(rr, j + 2);
            int r3 = __shfl(rr, j + 3);
            int r4 = __shfl(rr, j + 4);
            int r5 = __shfl(rr, j + 5);
            int r6 = __shfl(rr, j + 6);
            int r7 = __shfl(rr, j + 7);
            u16 u0 = src[(size_t)r0 * D + lane];   // 8 independent 128B-row gathers
            u16 u1 = src[(size_t)r1 * D + lane];
            u16 u2 = src[(size_t)r2 * D + lane];
            u16 u3 = src[(size_t)r3 * D + lane];
            u16 u4 = src[(size_t)r4 * D + lane];
            u16 u5 = src[(size_t)r5 * D + lane];
            u16 u6 = src[(size_t)r6 * D + lane];
            u16 u7 = src[(size_t)r7 * D + lane];
            acc += __half2float(__ushort_as_half(u0));
            acc += __half2float(__ushort_as_half(u1));
            acc += __half2float(__ushort_as_half(u2));
            acc += __half2float(__ushort_as_half(u3));
            acc += __half2float(__ushort_as_half(u4));
            acc += __half2float(__ushort_as_half(u5));
            acc += __half2float(__ushort_as_half(u6));
            acc += __half2float(__ushort_as_half(u7));
        }
        for (; j < cnt; ++j) {
            int r = __shfl(rr, j);
            acc += __half2float(__ushort_as_half(src[(size_t)r * D + lane]));
        }
    }
    float dc = dis[wave];
    float embs = dc * acc;
    size_t o = (size_t)wave * D + lane;
    if (WRITE_DST) dst[o] = __half_as_ushort(__float2half_rn(dc * embs));
    if (MODE == 0)      out[o] = emb[o] + embs;
    else if (MODE == 1) out[o] += embs;
    else                out[o] = (out[o] + embs) * 0.25f;
}

extern "C" void kernel_launch(void* const* d_in, const int* in_sizes, int n_in,
                              void* d_out, int out_size, void* d_ws, size_t ws_size,
                              hipStream_t stream) {
    const int* edge = (const int*)d_in[0];
    const float* emb = (const float*)d_in[1];
    const int E = in_sizes[0] / 2;       // 4,000,000
    const int N = in_sizes[1] / D;       // 150,000
    float* out = (float*)d_out;

    const int* row = edge;
    const int* col = edge + E;

    // workspace layout
    u16*   A       = (u16*)d_ws;                   // N*64 fp16 (Z ping)
    u16*   B       = A + (size_t)N * D;            // N*64 fp16 (Z pong)
    int*   srow    = (int*)(B + (size_t)N * D);    // E ints (sorted rows)
    int*   row_ptr = srow + E;                     // N+1 ints
    int*   deg     = row_ptr + N + 1;              // N ints
    int*   part    = deg + N;                      // N ints
    int*   cursor  = part + N;                     // N ints
    float* dis     = (float*)(cursor + N);         // N floats
    int*   bsum    = (int*)(dis + N);              // nb ints
    const int nb = (N + TPB - 1) / TPB;            // 586
    int*   boff    = bsum + nb;                    // nb ints

    const int edge_blocks = (E + TPB - 1) / TPB;
    const int node_blocks = nb;
    const int n = N * D;
    const int z_blocks = (n + TPB - 1) / TPB;
    const int spmm_blocks = (N * 64 + TPB - 1) / TPB;   // 1 wave per node

    // ---- build normalization + CSR (round-2-exact)
    hipMemsetAsync(deg, 0, (size_t)N * sizeof(int), stream);
    hist_kernel<<<edge_blocks, TPB, 0, stream>>>(col, deg, E);
    dis_kernel<<<node_blocks, TPB, 0, stream>>>(deg, dis, N);
    scan1_kernel<<<node_blocks, TPB, 0, stream>>>(deg, part, bsum, N);
    scan2_kernel<<<1, 1024, 0, stream>>>(bsum, boff, nb);
    scan3_kernel<<<node_blocks, TPB, 0, stream>>>(deg, part, boff, row_ptr, N, E);
    hipMemsetAsync(cursor, 0, (size_t)N * sizeof(int), stream);
    place_kernel<<<edge_blocks, TPB, 0, stream>>>(row, col, row_ptr, cursor, srow, E);

    // ---- Z0 = fp16(dis ⊙ emb)
    z0_kernel<<<z_blocks, TPB, 0, stream>>>(emb, dis, A, n);

    // ---- layer 1: out = emb + embs ; B = pre-scaled next state (fp16)
    spmm_kernel<0, true><<<spmm_blocks, TPB, 0, stream>>>(row_ptr, srow, dis, A, B,
                                                          out, emb, N);
    // ---- layer 2: out += embs ; A = next state
    spmm_kernel<1, true><<<spmm_blocks, TPB, 0, stream>>>(row_ptr, srow, dis, B, A,
                                                          out, emb, N);
    // ---- layer 3: out = (out + embs) * 0.25
    spmm_kernel<2, false><<<spmm_blocks, TPB, 0, stream>>>(row_ptr, srow, dis, A, nullptr,
                                                           out, emb, N);
}